// Round 5
// baseline (3538.499 us; speedup 1.0000x reference)
//
#include <hip/hip_runtime.h>
#include <math.h>

// B=128, H=512, T=1024, IN=8. Sequential RNN, S=1023 steps.
// Persistent kernel: 256 blocks x 512 threads (1 block/CU).
// v5 (resubmission -- round-4 run died to container failure twice with no
// counters; protocol/memory audit clean; ws/protocol identical to the
// passing r2/r3 kernels):
// ONE barrier per step. 64 groups x 4 j-blocks; group g = batches [2g,2g+2).
//   Block jb owns OUTPUT rows [jb*128, +128). Wave wv owns 16 COMPLETE rows
//   [jb*128+wv*16, +16) with full k=512: lane = (row r=lane&15, kq=lane>>4),
//   holds W_rec[row][kq*128..+128) = 32 float4 = 128 VGPRs.
// Step: poll own k-slice (tagged) -> stage h_{s-1} into padded LDS -> B1 ->
//   dot (LDS 16-lane-broadcast reads, conflict-free via 132-float quarters)
//   -> shfl_xor kq-reduce -> finalize+tanh -> tagged store. No partial-sum
//   barrier, no post-store barrier: stores leave per-wave as dots finish.
// h exchange: SELF-TAGGED fp32 (h +/-3 by phase (s>>1)&1), relaxed
//   agent-scope 4B atomics, 512 KB ping-pong ws (proven r2/r3). Safety chain
//   (one barrier suffices): store@s+1 > B1@s+1 > polls@s+1 (need all
//   stores@s) > B1@s > all polls@s  => overwrite of h_{s-1} data at iter
//   s+1 strictly follows every h_{s-1} read; phase bit disambiguates s-1
//   vs s+1 (differ by one phase) under per-location coherence. Deadlock-
//   free by induction: a wave blocked at poll@s already issued stores@s-1.
// key/prs: wave 7 of jb==0 only; kv handoff via readlane (no LDS flag).

#define BB  128
#define HH  512
#define TT  1024
#define SS  1023
#define NIN 8
#define NG  64      // groups
#define BPG 2       // batches per group
#define NJB 4       // j-blocks per group
#define JBS 128     // h rows per j-block
#define NTH 512
#define HBH (NG * BPG * HH)   // fp32 elems per ping-pong half (65536)
#define KQP 132               // padded quarter stride (128+4) -> bank offsets 0/4/8/12

#define BAR_LGKM() do {                                          \
    __builtin_amdgcn_sched_barrier(0);                           \
    __asm__ volatile("s_waitcnt lgkmcnt(0)" ::: "memory");       \
    __builtin_amdgcn_s_barrier();                                \
    __builtin_amdgcn_sched_barrier(0);                           \
} while (0)

__device__ __forceinline__ float bcast(float v, int ln) {
    return __int_as_float(__builtin_amdgcn_readlane(__float_as_int(v), ln));
}

__launch_bounds__(NTH, 2)
__global__ void rnn_persist(const float* __restrict__ inputs,   // [B][IN][T]
                            const float* __restrict__ W_in,     // [H][IN]
                            const float* __restrict__ b_in,     // [H]
                            const float* __restrict__ W_rec,    // [H][H]
                            const float* __restrict__ b_rec,    // [H]
                            const float* __restrict__ W_key,    // [2][H]
                            const float* __restrict__ b_key,    // [2]
                            float* __restrict__ out,
                            float* __restrict__ hbuf)           // [2][NG][BPG][HH] self-tagged
{
    const int tid  = threadIdx.x;
    const int lane = tid & 63;
    const int wv   = tid >> 6;            // 0..7
    const int g    = blockIdx.x & (NG - 1);   // same-XCD group: bid%8 == g%8
    const int jb   = blockIdx.x >> 6;     // 0..3
    const int b0   = g * BPG;
    const int j0   = jb * JBS;
    const int r    = lane & 15;           // row within wave's 16
    const int kq   = lane >> 4;           // k-quarter 0..3
    const int lrow = wv * 16 + r;         // row within block's 128

    float* keys_out = out;                         // [B][2][T]
    float* prs_out  = out + (size_t)BB * 2 * TT;   // [B][4][T]
    float* hs_out   = out + (size_t)BB * 6 * TT;   // [B][H][T]

    __shared__ float lds_h[2][BPG][4 * KQP];    // staged h_{s-1}, padded (4.2 KB x2)
    __shared__ float lds_hs[BPG * JBS * 33];    // 32-step hs accum, stride 33 (33.8 KB)
    __shared__ float lds_win[NIN][JBS];         // W_in slice (transposed)
    __shared__ float lds_wkey[2 * HH];
    __shared__ float lds_bias[JBS];             // b_in + b_rec
    __shared__ float lds_x2[2][BPG][NIN];       // x double buffer
    __shared__ float lds_bkey[2];

    // ---- W_rec: lane holds row (j0+lrow), k in [kq*128, +128) = 32 float4
    float4 wq[32];
    {
        const float4* wr = (const float4*)(W_rec + (size_t)(j0 + lrow) * HH + kq * 128);
        #pragma unroll
        for (int i = 0; i < 32; ++i) wq[i] = wr[i];
    }
    // ---- static LDS init
    for (int q = tid; q < NIN * JBS; q += NTH) {
        int i = q & 7, j = q >> 3;
        lds_win[i][j] = W_in[(size_t)(j0 + j) * NIN + i];
    }
    for (int i = tid; i < 2 * HH; i += NTH) lds_wkey[i] = W_key[i];
    if (tid < JBS) lds_bias[tid] = b_in[j0 + tid] + b_rec[j0 + tid];
    if (tid < 2)   lds_bkey[tid] = b_key[tid];
    for (int q = tid; q < BPG * JBS; q += NTH) lds_hs[q * 33] = 0.0f;  // zero col (t=0)

    // ---- zero t=0 slots for keys/prs
    if (jb == 0) {
        if (tid < BPG * 2) keys_out[((size_t)(b0 + (tid >> 1)) * 2 + (tid & 1)) * TT] = 0.0f;
        if (tid < BPG * 4) prs_out [((size_t)(b0 + (tid >> 2)) * 4 + (tid & 3)) * TT] = 0.0f;
    }

    // wave wv polls k-slice [wv*64, +64): 1 value/lane/batch
    const int   kpoll = wv * 64 + lane;               // k index this lane polls
    const int   sq    = kpoll >> 7;                   // its quarter
    const int   sj    = kpoll & 127;                  // offset in quarter
    const float* psrc = hbuf + (size_t)g * (BPG * HH) + kpoll;
    float*       pdst = hbuf + (size_t)g * (BPG * HH);

    __syncthreads();

    for (int s = 0; s < SS; ++s) {
        const int bufp = (s + 1) & 1;     // staged buffer holding h_{s-1} (= (s-1)&1)
        // -- stage x_s (wave 7 lanes 48..63; read post-B1)
        if (tid >= NTH - 16) {
            int t = tid - (NTH - 16), b = t >> 3, i = t & 7;
            lds_x2[s & 1][b][i] = inputs[(size_t)(b0 + b) * NIN * TT + (size_t)i * TT + (s + 1)];
        }
        // -- per-wave poll of self-tagged h_{s-1}; stage into padded LDS
        if (s > 0) {
            const float* p = psrc + (size_t)bufp * HBH;
            const int neg = ((s - 1) >> 1) & 1;     // producer iter s-1 phase
            const float off = neg ? -3.0f : 3.0f;
            float v0, v1;
            int rdy;
            do {
                v0 = __hip_atomic_load(p,      __ATOMIC_RELAXED, __HIP_MEMORY_SCOPE_AGENT);
                v1 = __hip_atomic_load(p + HH, __ATOMIC_RELAXED, __HIP_MEMORY_SCOPE_AGENT);
                rdy = neg ? ((v0 <= -1.5f) & (v1 <= -1.5f))
                          : ((v0 >=  1.5f) & (v1 >=  1.5f));
            } while (!__all(rdy));
            lds_h[bufp][0][sq * KQP + sj] = v0 - off;
            lds_h[bufp][1][sq * KQP + sj] = v1 - off;
        } else {
            lds_h[bufp][0][sq * KQP + sj] = 0.0f;
            lds_h[bufp][1][sq * KQP + sj] = 0.0f;
        }
        BAR_LGKM();                                   // B1: staged h complete

        // -- dot: full-k rows; 16-lane-broadcast LDS reads (conflict-free)
        float a0 = 0.f, a1 = 0.f;
        {
            const float4* h40 = (const float4*)&lds_h[bufp][0][kq * KQP];
            const float4* h41 = (const float4*)&lds_h[bufp][1][kq * KQP];
            #pragma unroll
            for (int q = 0; q < 32; ++q) {
                float4 w = wq[q];
                float4 x0 = h40[q], x1 = h41[q];
                a0 += w.x * x0.x + w.y * x0.y + w.z * x0.z + w.w * x0.w;
                a1 += w.x * x1.x + w.y * x1.y + w.z * x1.z + w.w * x1.w;
            }
        }
        // -- kq-reduce within wave (lanes r, r+16, r+32, r+48)
        a0 += __shfl_xor(a0, 16); a1 += __shfl_xor(a1, 16);
        a0 += __shfl_xor(a0, 32); a1 += __shfl_xor(a1, 32);

        if (lane < 16) {
            // -- finalize both batches for row (j0+lrow); tagged stores
            float pre0 = a0 + lds_bias[lrow];
            float pre1 = a1 + lds_bias[lrow];
            #pragma unroll
            for (int i = 0; i < NIN; ++i) {
                float wi = lds_win[i][lrow];
                pre0 += lds_x2[s & 1][0][i] * wi;
                pre1 += lds_x2[s & 1][1][i] * wi;
            }
            float h0 = tanhf(pre0), h1 = tanhf(pre1);
            float tagoff = ((s >> 1) & 1) ? -3.0f : 3.0f;
            __hip_atomic_store(&pdst[(size_t)(s & 1) * HBH + j0 + lrow], h0 + tagoff,
                               __ATOMIC_RELAXED, __HIP_MEMORY_SCOPE_AGENT);
            __hip_atomic_store(&pdst[(size_t)(s & 1) * HBH + HH + j0 + lrow], h1 + tagoff,
                               __ATOMIC_RELAXED, __HIP_MEMORY_SCOPE_AGENT);
            int slot = (s + 1) & 31;
            lds_hs[lrow * 33 + slot]               = h0;
            lds_hs[(JBS + lrow) * 33 + slot]       = h1;
        }

        // -- key_{s-1} + prs (wave 7 of jb==0 only; register kv handoff)
        if (jb == 0 && wv == 7) {
            float kv = 1.0f;                          // s==0: key_pre = 1
            int quad = lane >> 4, kb = quad >> 1, kc = quad & 1, seg = lane & 15;
            if (s > 0) {
                float p = 0.f;
                #pragma unroll
                for (int m = 0; m < 32; ++m) {
                    int k = seg + 16 * m;
                    p += lds_h[bufp][kb][(k >> 7) * KQP + (k & 127)] * lds_wkey[kc * HH + k];
                }
                p += __shfl_xor(p, 1); p += __shfl_xor(p, 2);
                p += __shfl_xor(p, 4); p += __shfl_xor(p, 8);
                kv = 1.0f / (1.0f + __expf(-(p + lds_bkey[kc])));
                if (seg == 0)
                    keys_out[((size_t)(b0 + kb) * 2 + kc) * TT + s] = kv;
            }
            float k0 = bcast(kv, 0);                  // (b=0,c=0)
            float k1 = bcast(kv, 32);                 // (b=1,c=0)
            if (lane < BPG * 4) {
                int b = lane >> 2, c = lane & 3;
                float kvb = b ? k1 : k0;
                const float* xb = lds_x2[s & 1][b];
                float tmv, arm;
                if (c < 2) { tmv = xb[6]; arm = xb[c]; }
                else       { tmv = xb[7]; arm = xb[c] * kvb + xb[c + 2] * (1.0f - kvb); }
                float rr = (tmv - arm) / (0.15f * arm);
                prs_out[((size_t)(b0 + b) * 4 + c) * TT + (s + 1)] = (tmv == 0.0f) ? 0.0f : rr * rr;
            }
        }

        // -- flush 32 accumulated hs slots (own-wave rows only; intra-wave order)
        if (((s + 1) & 31) == 31) {
            __builtin_amdgcn_sched_barrier(0);
            __asm__ volatile("s_waitcnt lgkmcnt(0)" ::: "memory");
            int u0 = s - 30;                  // multiple of 32
            int rb = lane >> 1, half = lane & 1;
            int b = rb >> 4, rr2 = rb & 15;
            int row_l = b * JBS + wv * 16 + rr2;
            float* dst = hs_out + ((size_t)(b0 + b) * HH + j0 + wv * 16 + rr2) * TT
                       + u0 + half * 16;
            const float* src = &lds_hs[row_l * 33 + half * 16];
            #pragma unroll
            for (int q = 0; q < 4; ++q) {
                float4 v = { src[4 * q], src[4 * q + 1], src[4 * q + 2], src[4 * q + 3] };
                *(float4*)(dst + 4 * q) = v;
            }
        }
    }

    // -- final key (slot T-1) from h_{S-1}: poll self-tagged buffer directly
    if (jb == 0 && wv == 7) {
        int quad = lane >> 4, kb = quad >> 1, kc = quad & 1, seg = lane & 15;
        // producer iter SS-1 = 1022: slot 0, phase (1022>>1)&1 = 1 -> f <= -1.5
        const float* hb = hbuf + (size_t)((SS - 1) & 1) * HBH
                        + (size_t)g * (BPG * HH) + (size_t)kb * HH;
        float p = 0.f;
        #pragma unroll
        for (int m = 0; m < 32; ++m) {
            int k = seg + 16 * m;
            float v;
            do {
                v = __hip_atomic_load(hb + k, __ATOMIC_RELAXED, __HIP_MEMORY_SCOPE_AGENT);
            } while (!(v <= -1.5f));
            p += (v + 3.0f) * lds_wkey[kc * HH + k];
        }
        p += __shfl_xor(p, 1); p += __shfl_xor(p, 2);
        p += __shfl_xor(p, 4); p += __shfl_xor(p, 8);
        if (seg == 0) {
            float kv = 1.0f / (1.0f + __expf(-(p + lds_bkey[kc])));
            keys_out[((size_t)(b0 + kb) * 2 + kc) * TT + (TT - 1)] = kv;
        }
    }
}

extern "C" void kernel_launch(void* const* d_in, const int* in_sizes, int n_in,
                              void* d_out, int out_size, void* d_ws, size_t ws_size,
                              hipStream_t stream) {
    const float* inputs = (const float*)d_in[0];
    const float* W_in   = (const float*)d_in[1];
    const float* b_in   = (const float*)d_in[2];
    const float* W_rec  = (const float*)d_in[3];
    const float* b_rec  = (const float*)d_in[4];
    const float* W_key  = (const float*)d_in[5];
    const float* b_key  = (const float*)d_in[6];
    float* outp = (float*)d_out;

    // ws layout: self-tagged h ping-pong buffer [2][NG][BPG][HH] fp32 = 512 KB
    // (same size/protocol as the r2/r3 PASSING kernels). memset(0) each
    // launch: encoded values live in [2,4] or [-4,-2], zero never ready.
    float* hbuf = (float*)d_ws;
    hipMemsetAsync(d_ws, 0, (size_t)2 * HBH * sizeof(float), stream);

    rnn_persist<<<dim3(NG * NJB), dim3(NTH), 0, stream>>>(
        inputs, W_in, b_in, W_rec, b_rec, W_key, b_key, outp, hbuf);
}

// Round 7
// 2709.653 us; speedup vs baseline: 1.3059x; 1.3059x over previous
//
#include <hip/hip_runtime.h>
#include <math.h>

// B=128, H=512, T=1024, IN=8. Sequential RNN, S=1023 steps.
// Persistent kernel: 256 blocks x 512 threads (1 block/CU).
// v6 RESUBMISSION: round-6 run died to "container failed twice" with no
// counters -- same signature as round 4, whose byte-identical resubmission
// then PASSED in round 5 (absmax 0.0625). Protocol/LDS/deadlock audit clean;
// exchange protocol identical to r2/r3/r5 passers.
//
// v6 = v4 structure (readlane dot BEFORE the barrier) + single barrier.
// 64 groups x 4 j-blocks; group g = batches [2g,2g+2).
//   Block jb owns W_rec rows [jb*128,+128): lane holds rows (lane, lane+64)
//   x k-slice [wv*64,+64) = 32 float4 = 128 regs.
// Step: poll own k-slice (self-tagged) -> readlane-broadcast dot (pure VALU,
//   pre-barrier, hides under exchange jitter) -> partials to db'd LDS -> B3
//   (ONLY barrier) -> waves 0-3: finalize (reg-resident W_in/bias, 8 LDS
//   partial reads, tanh, tagged store, hs-slot write, 32-step flush);
//   waves 4-7: straight to next poll (overlaps remote store RTT+detect with
//   finalize). lds_part/lds_chunk/lds_x2 double-buffered on s&1 -> no B4.
// h exchange: SELF-TAGGED fp32 (h +/-3 by phase (s>>1)&1), relaxed
//   agent-scope 4B atomics, 512 KB ping-pong ws (proven r2/r3/r5).
//   Overwrite safety (one barrier): store@s+2(slot s&1) <= P.B3@s+2 <=
//   P.polls@s+2 <= stores@s+1 (all blocks) <= their B3@s+1 <= ALL waves'
//   polls@s+1 done. Staleness: per-location coherence + phase bit (v5-proven).
//   Deadlock-free by induction: a wave blocked at poll@s already issued its
//   stores@s-1 (program order).
// key/prs: wave 7 of jb==0, post-barrier, from db'd lds_chunk; kv via readlane.

#define BB  128
#define HH  512
#define TT  1024
#define SS  1023
#define NIN 8
#define NG  64      // groups
#define BPG 2       // batches per group
#define NJB 4       // j-blocks per group
#define JBS 128     // h rows per j-block
#define NTH 512
#define HBH (NG * BPG * HH)   // fp32 elems per ping-pong half (65536)

#define BAR_LGKM() do {                                          \
    __builtin_amdgcn_sched_barrier(0);                           \
    __asm__ volatile("s_waitcnt lgkmcnt(0)" ::: "memory");       \
    __builtin_amdgcn_s_barrier();                                \
    __builtin_amdgcn_sched_barrier(0);                           \
} while (0)

__device__ __forceinline__ float bcast(float v, int ln) {
    return __int_as_float(__builtin_amdgcn_readlane(__float_as_int(v), ln));
}

__launch_bounds__(NTH, 2)
__global__ void rnn_persist(const float* __restrict__ inputs,   // [B][IN][T]
                            const float* __restrict__ W_in,     // [H][IN]
                            const float* __restrict__ b_in,     // [H]
                            const float* __restrict__ W_rec,    // [H][H]
                            const float* __restrict__ b_rec,    // [H]
                            const float* __restrict__ W_key,    // [2][H]
                            const float* __restrict__ b_key,    // [2]
                            float* __restrict__ out,
                            float* __restrict__ hbuf)           // [2][NG][BPG][HH] self-tagged
{
    const int tid  = threadIdx.x;
    const int lane = tid & 63;
    const int wv   = tid >> 6;            // 0..7
    const int g    = blockIdx.x & (NG - 1);   // same-XCD group: bid%8 == g%8
    const int jb   = blockIdx.x >> 6;     // 0..3
    const int b0   = g * BPG;
    const int j0   = jb * JBS;

    float* keys_out = out;                         // [B][2][T]
    float* prs_out  = out + (size_t)BB * 2 * TT;   // [B][4][T]
    float* hs_out   = out + (size_t)BB * 6 * TT;   // [B][H][T]

    __shared__ float lds_chunk[2][8][BPG][64];  // h_{s-1} for key dot, db (8 KB)
    __shared__ float lds_part[2][8][BPG][JBS];  // partials, db (16 KB)
    __shared__ float lds_hs[BPG * JBS * 33];    // 32-step hs accum, stride 33 (33.8 KB)
    __shared__ float lds_wkey[2 * HH];
    __shared__ float lds_x2[2][BPG][NIN];       // x double buffer
    __shared__ float lds_bkey[2];

    // ---- W_rec slice -> registers: 2 rows x 64 k = 32 float4 = 128 regs
    float4 w0[16], w1[16];
    {
        const float4* wr0 = (const float4*)(W_rec + (size_t)(j0 + lane) * HH + wv * 64);
        const float4* wr1 = (const float4*)(W_rec + (size_t)(j0 + 64 + lane) * HH + wv * 64);
        #pragma unroll
        for (int i = 0; i < 16; ++i) { w0[i] = wr0[i]; w1[i] = wr1[i]; }
    }
    // ---- finalize lanes (tid<256) preload W_in row + bias into registers
    float winreg[NIN];
    float biasreg = 0.0f;
    const int fb = tid >> 7;              // finalize batch (0/1)
    const int fj = tid & 127;             // finalize row within block
    if (tid < BPG * JBS) {
        #pragma unroll
        for (int i = 0; i < NIN; ++i) winreg[i] = W_in[(size_t)(j0 + fj) * NIN + i];
        biasreg = b_in[j0 + fj] + b_rec[j0 + fj];
    }
    // ---- static LDS init
    for (int i = tid; i < 2 * HH; i += NTH) lds_wkey[i] = W_key[i];
    if (tid < 2) lds_bkey[tid] = b_key[tid];
    for (int q = tid; q < BPG * JBS; q += NTH) lds_hs[q * 33] = 0.0f;  // zero col (t=0)

    // ---- zero t=0 slots for keys/prs
    if (jb == 0) {
        if (tid < BPG * 2) keys_out[((size_t)(b0 + (tid >> 1)) * 2 + (tid & 1)) * TT] = 0.0f;
        if (tid < BPG * 4) prs_out [((size_t)(b0 + (tid >> 2)) * 4 + (tid & 3)) * TT] = 0.0f;
    }

    // wave wv polls k-slice [wv*64,+64): 1 value/lane/batch
    const float* psrc = hbuf + (size_t)g * (BPG * HH) + wv * 64 + lane;
    float*       pdst = hbuf + (size_t)g * (BPG * HH);

    __syncthreads();

    for (int s = 0; s < SS; ++s) {
        // -- stage x_s (wave 7 lanes 48..63; consumed post-B3)
        if (tid >= NTH - 16) {
            int t = tid - (NTH - 16), b = t >> 3, i = t & 7;
            lds_x2[s & 1][b][i] = inputs[(size_t)(b0 + b) * NIN * TT + (size_t)i * TT + (s + 1)];
        }
        // -- per-wave poll of self-tagged h_{s-1}; poll IS the fetch
        float h0, h1;
        if (s > 0) {
            const float* p = psrc + (size_t)((s - 1) & 1) * HBH;
            const int neg = ((s - 1) >> 1) & 1;     // producer iter s-1 phase
            const float off = neg ? -3.0f : 3.0f;
            float v0, v1;
            int rdy;
            do {
                v0 = __hip_atomic_load(p,      __ATOMIC_RELAXED, __HIP_MEMORY_SCOPE_AGENT);
                v1 = __hip_atomic_load(p + HH, __ATOMIC_RELAXED, __HIP_MEMORY_SCOPE_AGENT);
                rdy = neg ? ((v0 <= -1.5f) & (v1 <= -1.5f))
                          : ((v0 >=  1.5f) & (v1 >=  1.5f));
            } while (!__all(rdy));
            h0 = v0 - off;
            h1 = v1 - off;
        } else {
            h0 = 0.0f;
            h1 = 0.0f;
        }
        if (jb == 0) {                      // stage for key dot (db'd)
            lds_chunk[s & 1][wv][0][lane] = h0;
            lds_chunk[s & 1][wv][1][lane] = h1;
        }

        // -- dot: register-broadcast h via readlane, pure VALU, PRE-barrier.
        //    8 accumulators halve the dependent-FMA chain.
        {
            float a00 = 0.f, a01 = 0.f, a10 = 0.f, a11 = 0.f;
            float c00 = 0.f, c01 = 0.f, c10 = 0.f, c11 = 0.f;
            #pragma unroll
            for (int q = 0; q < 16; ++q) {
                const float* wa = (const float*)&w0[q];
                const float* wb = (const float*)&w1[q];
                #pragma unroll
                for (int c = 0; c < 4; ++c) {
                    const int ln = q * 4 + c;
                    float s0 = bcast(h0, ln);       // h[k=wv*64+ln][b=0]
                    float s1 = bcast(h1, ln);       // h[k=wv*64+ln][b=1]
                    if (q & 1) {
                        c00 += wa[c] * s0; c01 += wa[c] * s1;
                        c10 += wb[c] * s0; c11 += wb[c] * s1;
                    } else {
                        a00 += wa[c] * s0; a01 += wa[c] * s1;
                        a10 += wb[c] * s0; a11 += wb[c] * s1;
                    }
                }
            }
            a00 += c00; a01 += c01; a10 += c10; a11 += c11;
            lds_part[s & 1][wv][0][lane]      = a00;
            lds_part[s & 1][wv][1][lane]      = a01;
            lds_part[s & 1][wv][0][lane + 64] = a10;
            lds_part[s & 1][wv][1][lane + 64] = a11;
        }
        BAR_LGKM();                                   // B3: the ONLY barrier

        if (tid < BPG * JBS) {
            // -- finalize h_s for (fb, fj); reg W_in/bias; tagged store
            float pre = biasreg;
            #pragma unroll
            for (int w = 0; w < 8; ++w) pre += lds_part[s & 1][w][fb][fj];
            #pragma unroll
            for (int i = 0; i < NIN; ++i) pre += lds_x2[s & 1][fb][i] * winreg[i];
            float hv = tanhf(pre);
            float enc = hv + (((s >> 1) & 1) ? -3.0f : 3.0f);
            __hip_atomic_store(&pdst[(size_t)(s & 1) * HBH + (size_t)fb * HH + j0 + fj], enc,
                               __ATOMIC_RELAXED, __HIP_MEMORY_SCOPE_AGENT);
            lds_hs[(fb * JBS + fj) * 33 + ((s + 1) & 31)] = hv;
            __builtin_amdgcn_sched_barrier(0);        // pin store before next poll

            // -- flush 32 accumulated hs slots for OWN row (intra-lane order)
            if (((s + 1) & 31) == 31) {
                __asm__ volatile("s_waitcnt lgkmcnt(0)" ::: "memory");
                int u0 = s - 30;                  // multiple of 32
                float* dst = hs_out + ((size_t)(b0 + fb) * HH + j0 + fj) * TT + u0;
                const float* src = &lds_hs[(fb * JBS + fj) * 33];
                #pragma unroll
                for (int q = 0; q < 8; ++q) {
                    float4 v = { src[4 * q], src[4 * q + 1], src[4 * q + 2], src[4 * q + 3] };
                    *(float4*)(dst + 4 * q) = v;
                }
            }
        } else if (jb == 0 && wv == 7) {
            // -- key_{s-1} + prs from db'd chunk/x2; kv handoff via readlane
            float kv = 1.0f;                          // s==0: key_pre = 1
            int quad = lane >> 4, kb = quad >> 1, kc = quad & 1, seg = lane & 15;
            if (s > 0) {
                float p = 0.f;
                #pragma unroll
                for (int m = 0; m < 32; ++m) {
                    int k = seg + 16 * m;
                    p += lds_chunk[s & 1][k >> 6][kb][k & 63] * lds_wkey[kc * HH + k];
                }
                p += __shfl_xor(p, 1); p += __shfl_xor(p, 2);
                p += __shfl_xor(p, 4); p += __shfl_xor(p, 8);
                kv = 1.0f / (1.0f + __expf(-(p + lds_bkey[kc])));
                if (seg == 0)
                    keys_out[((size_t)(b0 + kb) * 2 + kc) * TT + s] = kv;
            }
            float k0 = bcast(kv, 0);                  // (b=0,c=0)
            float k1 = bcast(kv, 32);                 // (b=1,c=0)
            if (lane < BPG * 4) {
                int b = lane >> 2, c = lane & 3;
                float kvb = b ? k1 : k0;
                const float* xb = lds_x2[s & 1][b];
                float tmv, arm;
                if (c < 2) { tmv = xb[6]; arm = xb[c]; }
                else       { tmv = xb[7]; arm = xb[c] * kvb + xb[c + 2] * (1.0f - kvb); }
                float rr = (tmv - arm) / (0.15f * arm);
                prs_out[((size_t)(b0 + b) * 4 + c) * TT + (s + 1)] = (tmv == 0.0f) ? 0.0f : rr * rr;
            }
        }
        // NO second barrier: lds_part/lds_chunk/lds_x2 are double-buffered;
        // next-iteration writes to [s^1] buffers can't race this step's reads,
        // and writes back to [s&1] happen only after B3@s+1 (ordered).
    }

    // -- final key (slot T-1) from h_{S-1}: poll self-tagged buffer directly
    if (jb == 0 && wv == 7) {
        int quad = lane >> 4, kb = quad >> 1, kc = quad & 1, seg = lane & 15;
        // producer iter SS-1 = 1022: slot 0, phase (1022>>1)&1 = 1 -> f <= -1.5
        const float* hb = hbuf + (size_t)((SS - 1) & 1) * HBH
                        + (size_t)g * (BPG * HH) + (size_t)kb * HH;
        float p = 0.f;
        #pragma unroll
        for (int m = 0; m < 32; ++m) {
            int k = seg + 16 * m;
            float v;
            do {
                v = __hip_atomic_load(hb + k, __ATOMIC_RELAXED, __HIP_MEMORY_SCOPE_AGENT);
            } while (!(v <= -1.5f));
            p += (v + 3.0f) * lds_wkey[kc * HH + k];
        }
        p += __shfl_xor(p, 1); p += __shfl_xor(p, 2);
        p += __shfl_xor(p, 4); p += __shfl_xor(p, 8);
        if (seg == 0) {
            float kv = 1.0f / (1.0f + __expf(-(p + lds_bkey[kc])));
            keys_out[((size_t)(b0 + kb) * 2 + kc) * TT + (TT - 1)] = kv;
        }
    }
}

extern "C" void kernel_launch(void* const* d_in, const int* in_sizes, int n_in,
                              void* d_out, int out_size, void* d_ws, size_t ws_size,
                              hipStream_t stream) {
    const float* inputs = (const float*)d_in[0];
    const float* W_in   = (const float*)d_in[1];
    const float* b_in   = (const float*)d_in[2];
    const float* W_rec  = (const float*)d_in[3];
    const float* b_rec  = (const float*)d_in[4];
    const float* W_key  = (const float*)d_in[5];
    const float* b_key  = (const float*)d_in[6];
    float* outp = (float*)d_out;

    // ws layout: self-tagged h ping-pong buffer [2][NG][BPG][HH] fp32 = 512 KB
    // (same size/protocol as the r2/r3/r5 PASSING kernels). memset(0) each
    // launch: encoded values live in [2,4] or [-4,-2], zero never ready.
    float* hbuf = (float*)d_ws;
    hipMemsetAsync(d_ws, 0, (size_t)2 * HBH * sizeof(float), stream);

    rnn_persist<<<dim3(NG * NJB), dim3(NTH), 0, stream>>>(
        inputs, W_in, b_in, W_rec, b_rec, W_key, b_key, outp, hbuf);
}

// Round 9
// 2603.923 us; speedup vs baseline: 1.3589x; 1.0406x over previous
//
#include <hip/hip_runtime.h>
#include <math.h>

// B=128, H=512, T=1024, IN=8. Sequential RNN, S=1023 steps.
// Persistent kernel: 256 blocks x 512 threads (1 block/CU).
// v7b = v4 (best, 2570us) + NON-TEMPORAL output/input traffic.
//   (v7 failed COMPILE only: __builtin_nontemporal_store rejects HIP float4;
//    fixed with a native ext_vector_type(4) alias. Semantics unchanged.)
//   Theory: WRITE_SIZE 527MB = outputs(265) + h-exchange writebacks(262);
//   FETCH_SIZE 155MB >> 6MB unique inputs => ~15-18% of poll loads miss L2
//   (hs_out streaming evicts the 512KB exchange buffer) and pay ~900cy HBM
//   latency inside the serial recurrence. nt stores/loads keep L2 clean so
//   the exchange stays L2-resident.
// Geometry (v4): 64 groups x 4 j-blocks; group g = batches [2g,2g+2).
//   Block jb owns W_rec rows [jb*128,+128): lane holds rows (lane, lane+64)
//   x k-slice [wv*64,+64) = 32 float4 = 128 regs.
// h exchange: SELF-TAGGED fp32 (h +/-3 by phase (s>>1)&1), poll-on-data,
//   relaxed agent-scope 4B atomics, 512 KB ping-pong ws (r2/r3/r5/r7 proven).
// Dot: readlane-broadcast, pure VALU, pre-barrier. Two barriers (B3, B4)
//   exactly as v4 (v6 showed removing B4 regresses: freer spin hurts).

#define BB  128
#define HH  512
#define TT  1024
#define SS  1023
#define NIN 8
#define NG  64      // groups
#define BPG 2       // batches per group
#define NJB 4       // j-blocks per group
#define JBS 128     // h rows per j-block
#define NTH 512
#define HBH (NG * BPG * HH)   // fp32 elems per ping-pong half (65536)

typedef float f32x4 __attribute__((ext_vector_type(4)));   // nt-store-able 16B

#define BAR_LGKM() do {                                          \
    __builtin_amdgcn_sched_barrier(0);                           \
    __asm__ volatile("s_waitcnt lgkmcnt(0)" ::: "memory");       \
    __builtin_amdgcn_s_barrier();                                \
    __builtin_amdgcn_sched_barrier(0);                           \
} while (0)

__device__ __forceinline__ float bcast(float v, int ln) {
    return __int_as_float(__builtin_amdgcn_readlane(__float_as_int(v), ln));
}

__launch_bounds__(NTH, 2)
__global__ void rnn_persist(const float* __restrict__ inputs,   // [B][IN][T]
                            const float* __restrict__ W_in,     // [H][IN]
                            const float* __restrict__ b_in,     // [H]
                            const float* __restrict__ W_rec,    // [H][H]
                            const float* __restrict__ b_rec,    // [H]
                            const float* __restrict__ W_key,    // [2][H]
                            const float* __restrict__ b_key,    // [2]
                            float* __restrict__ out,
                            float* __restrict__ hbuf)           // [2][NG][BPG][HH] self-tagged
{
    const int tid  = threadIdx.x;
    const int lane = tid & 63;
    const int wv   = tid >> 6;            // 0..7
    const int g    = blockIdx.x & (NG - 1);   // same-XCD group: bid%8 == g%8
    const int jb   = blockIdx.x >> 6;     // 0..3
    const int b0   = g * BPG;
    const int j0   = jb * JBS;

    float* keys_out = out;                         // [B][2][T]
    float* prs_out  = out + (size_t)BB * 2 * TT;   // [B][4][T]
    float* hs_out   = out + (size_t)BB * 6 * TT;   // [B][H][T]

    __shared__ float lds_chunk[8][BPG][64];     // h_{s-1} for key dot (jb==0)
    __shared__ float lds_part[8][BPG][JBS];     // [wave][b][j] partials (8 KB)
    __shared__ float lds_hs[BPG * JBS * 33];    // 32-step hs accum, stride 33
    __shared__ float lds_win[NIN][JBS];         // W_in slice (transposed)
    __shared__ float lds_wkey[2 * HH];
    __shared__ float lds_bias[JBS];             // b_in + b_rec
    __shared__ float lds_x2[2][BPG][NIN];       // x double buffer
    __shared__ float lds_key[BPG];              // key_{s-1}[b][0]
    __shared__ float lds_bkey[2];

    // ---- W_rec slice -> registers: 2 rows x 64 k = 32 float4 = 128 regs
    float4 w0[16], w1[16];
    {
        const float4* wr0 = (const float4*)(W_rec + (size_t)(j0 + lane) * HH + wv * 64);
        const float4* wr1 = (const float4*)(W_rec + (size_t)(j0 + 64 + lane) * HH + wv * 64);
        #pragma unroll
        for (int i = 0; i < 16; ++i) { w0[i] = wr0[i]; w1[i] = wr1[i]; }
    }
    // ---- static LDS init
    for (int r = tid; r < NIN * JBS; r += NTH) {
        int i = r & 7, j = r >> 3;
        lds_win[i][j] = W_in[(size_t)(j0 + j) * NIN + i];
    }
    for (int i = tid; i < 2 * HH; i += NTH) lds_wkey[i] = W_key[i];
    if (tid < JBS) lds_bias[tid] = b_in[j0 + tid] + b_rec[j0 + tid];
    if (tid < BPG) lds_key[tid] = 1.0f;
    if (tid < 2)   lds_bkey[tid] = b_key[tid];
    for (int r = tid; r < BPG * JBS; r += NTH) lds_hs[r * 33] = 0.0f;  // zero col

    // ---- zero t=0 slots for keys/prs (nt: output traffic)
    if (jb == 0) {
        if (tid < BPG * 2)
            __builtin_nontemporal_store(0.0f,
                &keys_out[((size_t)(b0 + (tid >> 1)) * 2 + (tid & 1)) * TT]);
        if (tid < BPG * 4)
            __builtin_nontemporal_store(0.0f,
                &prs_out[((size_t)(b0 + (tid >> 2)) * 4 + (tid & 3)) * TT]);
    }

    // wave wv polls k-slice [wv*64, +64): 1 value/lane/batch
    const float* psrc = hbuf + (size_t)g * (BPG * HH) + wv * 64 + lane;
    float*       pdst = hbuf + (size_t)g * (BPG * HH);

    __syncthreads();

    for (int s = 0; s < SS; ++s) {
        // -- stage x_s (nt loads: streaming input, keep L2 for the exchange)
        if (tid >= NTH - 16) {
            int t = tid - (NTH - 16), b = t >> 3, i = t & 7;
            lds_x2[s & 1][b][i] = __builtin_nontemporal_load(
                &inputs[(size_t)(b0 + b) * NIN * TT + (size_t)i * TT + (s + 1)]);
        }
        // -- per-wave poll of self-tagged h_{s-1}; poll IS the fetch
        float h0, h1;
        if (s > 0) {
            const float* p = psrc + (size_t)((s - 1) & 1) * HBH;
            const int neg = ((s - 1) >> 1) & 1;     // producer iter s-1 phase
            const float off = neg ? -3.0f : 3.0f;
            float v0, v1;
            int rdy;
            do {
                v0 = __hip_atomic_load(p,      __ATOMIC_RELAXED, __HIP_MEMORY_SCOPE_AGENT);
                v1 = __hip_atomic_load(p + HH, __ATOMIC_RELAXED, __HIP_MEMORY_SCOPE_AGENT);
                rdy = neg ? ((v0 <= -1.5f) & (v1 <= -1.5f))
                          : ((v0 >=  1.5f) & (v1 >=  1.5f));
            } while (!__all(rdy));
            h0 = v0 - off;
            h1 = v1 - off;
        } else {
            h0 = 0.0f;
            h1 = 0.0f;
        }
        if (jb == 0) {                      // stage for key dot
            lds_chunk[wv][0][lane] = h0;
            lds_chunk[wv][1][lane] = h1;
        }

        // -- dot: register-broadcast h via readlane, pure VALU (no LDS)
        {
            float a00 = 0.f, a01 = 0.f, a10 = 0.f, a11 = 0.f;
            #pragma unroll
            for (int q = 0; q < 16; ++q) {
                const float* wa = (const float*)&w0[q];
                const float* wb = (const float*)&w1[q];
                #pragma unroll
                for (int c = 0; c < 4; ++c) {
                    const int ln = q * 4 + c;
                    float s0 = bcast(h0, ln);       // h[k=wv*64+ln][b=0]
                    float s1 = bcast(h1, ln);       // h[k=wv*64+ln][b=1]
                    float wva = wa[c];              // W_rec[row=lane   ][k]
                    float wvb = wb[c];              // W_rec[row=lane+64][k]
                    a00 += wva * s0; a01 += wva * s1;
                    a10 += wvb * s0; a11 += wvb * s1;
                }
            }
            lds_part[wv][0][lane]      = a00;
            lds_part[wv][1][lane]      = a01;
            lds_part[wv][0][lane + 64] = a10;
            lds_part[wv][1][lane + 64] = a11;
        }
        BAR_LGKM();                                        // B3

        if (tid < BPG * JBS) {
            // -- finalize h_s for (b, j); self-tagged store (no drain, no flag)
            int b = tid >> 7, j = tid & 127;
            float pre = lds_bias[j];
            #pragma unroll
            for (int w = 0; w < 8; ++w) pre += lds_part[w][b][j];
            #pragma unroll
            for (int i = 0; i < NIN; ++i) pre += lds_x2[s & 1][b][i] * lds_win[i][j];
            float hv = tanhf(pre);
            float enc = hv + (((s >> 1) & 1) ? -3.0f : 3.0f);
            __hip_atomic_store(&pdst[(size_t)(s & 1) * HBH + (size_t)b * HH + j0 + j], enc,
                               __ATOMIC_RELAXED, __HIP_MEMORY_SCOPE_AGENT);
            lds_hs[(b * JBS + j) * 33 + ((s + 1) & 31)] = hv;
        } else if (jb == 0 && s > 0 && tid < 384) {
            // -- key_{s-1} = sigmoid(h_{s-1} @ W_key^T + b_key); h from chunks
            int t2  = tid - 256;
            int dot = t2 >> 5;          // 0..3
            int b = dot >> 1, c = dot & 1, seg = t2 & 31;
            float p = 0.f;
            #pragma unroll
            for (int m = 0; m < 16; ++m) {
                int k = seg + 32 * m;
                p += lds_chunk[k >> 6][b][k & 63] * lds_wkey[c * HH + k];
            }
            #pragma unroll
            for (int off = 16; off > 0; off >>= 1) p += __shfl_down(p, off, 32);
            if (seg == 0) {
                float kv = 1.0f / (1.0f + __expf(-(p + lds_bkey[c])));
                __builtin_nontemporal_store(kv,
                    &keys_out[((size_t)(b0 + b) * 2 + c) * TT + s]);
                if (c == 0) lds_key[b] = kv;
            }
        }
        BAR_LGKM();                                        // B4

        // -- prs (off critical path; nt store)
        if (jb == 0 && tid < BPG * 4) {
            int b = tid >> 2, c = tid & 3;
            float kv = lds_key[b];
            const float* xb = lds_x2[s & 1][b];
            float tmv, arm;
            if (c < 2) { tmv = xb[6]; arm = xb[c]; }
            else       { tmv = xb[7]; arm = xb[c] * kv + xb[c + 2] * (1.0f - kv); }
            float r = (tmv - arm) / (0.15f * arm);
            __builtin_nontemporal_store((tmv == 0.0f) ? 0.0f : r * r,
                &prs_out[((size_t)(b0 + b) * 4 + c) * TT + (s + 1)]);
        }

        // -- flush 32 accumulated hs time-slots (nt stores: the L2 polluter)
        if (((s + 1) & 31) == 31) {
            int u0 = s - 30;                  // multiple of 32
            int r = tid >> 1, half = tid & 1;
            int b = r >> 7, j = r & 127;
            float* dst = hs_out + ((size_t)(b0 + b) * HH + j0 + j) * TT + u0 + half * 16;
            const float* src = &lds_hs[r * 33 + half * 16];
            #pragma unroll
            for (int q = 0; q < 4; ++q) {
                f32x4 v = { src[4 * q], src[4 * q + 1], src[4 * q + 2], src[4 * q + 3] };
                __builtin_nontemporal_store(v, (f32x4*)(dst + 4 * q));
            }
        }
    }

    // -- final key (slot T-1) from h_{S-1}: poll self-tagged buffer directly
    if (jb == 0 && tid >= 256 && tid < 384) {
        int t2  = tid - 256;
        int dot = t2 >> 5;          // 0..3
        int b = dot >> 1, c = dot & 1, seg = t2 & 31;
        // producer iter SS-1 = 1022: phase (1022>>1)&1 = 1 -> f <= -1.5
        const float* hb = hbuf + (size_t)((SS - 1) & 1) * HBH
                        + (size_t)g * (BPG * HH) + (size_t)b * HH;
        float p = 0.f;
        #pragma unroll
        for (int m = 0; m < 16; ++m) {
            int k = seg + 32 * m;
            float v;
            do {
                v = __hip_atomic_load(hb + k, __ATOMIC_RELAXED, __HIP_MEMORY_SCOPE_AGENT);
            } while (!(v <= -1.5f));
            p += (v + 3.0f) * lds_wkey[c * HH + k];
        }
        #pragma unroll
        for (int off = 16; off > 0; off >>= 1) p += __shfl_down(p, off, 32);
        if (seg == 0) {
            float kv = 1.0f / (1.0f + __expf(-(p + lds_bkey[c])));
            __builtin_nontemporal_store(kv,
                &keys_out[((size_t)(b0 + b) * 2 + c) * TT + (TT - 1)]);
        }
    }
}

extern "C" void kernel_launch(void* const* d_in, const int* in_sizes, int n_in,
                              void* d_out, int out_size, void* d_ws, size_t ws_size,
                              hipStream_t stream) {
    const float* inputs = (const float*)d_in[0];
    const float* W_in   = (const float*)d_in[1];
    const float* b_in   = (const float*)d_in[2];
    const float* W_rec  = (const float*)d_in[3];
    const float* b_rec  = (const float*)d_in[4];
    const float* W_key  = (const float*)d_in[5];
    const float* b_key  = (const float*)d_in[6];
    float* outp = (float*)d_out;

    // ws layout: self-tagged h ping-pong buffer [2][NG][BPG][HH] fp32 = 512 KB
    // (same size/protocol as all passing rounds). memset(0) each launch:
    // encoded values live in [2,4] or [-4,-2], zero never reads as ready.
    float* hbuf = (float*)d_ws;
    (void)hipMemsetAsync(d_ws, 0, (size_t)2 * HBH * sizeof(float), stream);

    rnn_persist<<<dim3(NG * NJB), dim3(NTH), 0, stream>>>(
        inputs, W_in, b_in, W_rec, b_rec, W_key, b_key, outp, hbuf);
}